// Round 1
// baseline (123.207 us; speedup 1.0000x reference)
//
#include <hip/hip_runtime.h>
#include <math.h>

// Problem: B=4096, K=128, D=256 (fixed by setup_inputs).
// out[b,d] = sqrt(1-e) * sum_k p_k * (x - a*c)/var,  var = e*(s^2-1)+1
// lp_k = -0.5*S1 - 128*ln2*S2 + ln w_k   (k-uniform const dropped)
//   S1 = sum_d diff^2/var, S2 = sum_d log2(var)

constexpr int Kc = 128;
constexpr int Dc = 256;
constexpr int G  = 2;   // batch rows per block (amortizes table L2 reads)

// ---- prep: transpose centers and stds^2-1 into ws for pass-1 coalescing ----
__global__ void prep_kernel(const float* __restrict__ centers,
                            const float* __restrict__ stds,
                            float* __restrict__ CT, float* __restrict__ AT) {
    int idx = blockIdx.x * blockDim.x + threadIdx.x;   // over D*K, write-coalesced
    if (idx >= Kc * Dc) return;
    int d = idx >> 7;        // idx / K
    int k = idx & (Kc - 1);  // idx % K
    float c = centers[k * Dc + d];
    float s = stds[k * Dc + d];
    CT[idx] = c;
    AT[idx] = s * s - 1.0f;
}

__global__ __launch_bounds__(256) void score_kernel(
    const float* __restrict__ x, const float* __restrict__ t,
    const float* __restrict__ centers, const float* __restrict__ stds,
    const float* __restrict__ weights,
    const float* __restrict__ CT, const float* __restrict__ AT,
    float* __restrict__ out)
{
    const int b0  = blockIdx.x * G;
    const int tid = threadIdx.x;

    __shared__ float x_lds[G][Dc];
    __shared__ float part1[G][2][Kc];
    __shared__ float partL[G][2][Kc];
    __shared__ float pn[G][Kc];
    __shared__ float wmax[G][2];
    __shared__ float wsum[G][2];

    // per-row scalars (uniform; cheap to recompute per thread)
    float e[G], na[G], onee[G], sg[G];
    #pragma unroll
    for (int g = 0; g < G; ++g) {
        float tt = t[b0 + g];
        float Bt = 0.1f * tt + 9.95f * tt * tt;     // BETA_MIN*t + 0.5*(BMAX-BMIN)*t^2
        float ee = expf(-Bt);
        e[g]    = ee;
        na[g]   = -sqrtf(ee);                       // -a = -exp(-Bt/2)
        onee[g] = 1.0f - ee;
        sg[g]   = sqrtf(1.0f - ee);
    }

    // stage x rows
    #pragma unroll
    for (int g = 0; g < G; ++g)
        x_lds[g][tid] = x[(b0 + g) * Dc + tid];
    __syncthreads();

    // ---------------- pass 1: lp partials, thread = (k, half-of-D) ----------------
    const int kk    = tid & (Kc - 1);
    const int half  = tid >> 7;
    const int dbase = half * (Dc / 2);

    float acc1[G] = {0.0f, 0.0f};
    float accL[G] = {0.0f, 0.0f};
    for (int dd = 0; dd < Dc / 2; dd += 8) {
        float prod[G] = {1.0f, 1.0f};
        #pragma unroll
        for (int j = 0; j < 8; ++j) {
            int d   = dbase + dd + j;
            float c = CT[d * Kc + kk];   // coalesced: consecutive kk
            float A = AT[d * Kc + kk];
            #pragma unroll
            for (int g = 0; g < G; ++g) {
                float var  = fmaf(e[g], A, 1.0f);           // in [0.25, 1]
                float rv   = __builtin_amdgcn_rcpf(var);
                float diff = fmaf(na[g], c, x_lds[g][d]);   // LDS broadcast
                acc1[g] = fmaf(diff * diff, rv, acc1[g]);
                prod[g] *= var;                             // >= 0.25^8, no underflow
            }
        }
        #pragma unroll
        for (int g = 0; g < G; ++g)
            accL[g] += __log2f(prod[g]);                    // 1 log per 8 elements
    }
    #pragma unroll
    for (int g = 0; g < G; ++g) {
        part1[g][half][kk] = acc1[g];
        partL[g][half][kk] = accL[g];
    }
    __syncthreads();

    // ---------------- softmax over k (threads < K, 2 waves) ----------------
    float lp[G], pe[G];
    if (tid < Kc) {
        float lw = __logf(weights[tid]);
        #pragma unroll
        for (int g = 0; g < G; ++g) {
            float S1 = part1[g][0][tid] + part1[g][1][tid];
            float S2 = partL[g][0][tid] + partL[g][1][tid];
            lp[g] = fmaf(-0.5f, S1, fmaf(-88.72283911167299f, S2, lw)); // 128*ln2
            float m = lp[g];
            #pragma unroll
            for (int off = 32; off > 0; off >>= 1)
                m = fmaxf(m, __shfl_xor(m, off, 64));
            if ((tid & 63) == 0) wmax[g][tid >> 6] = m;
        }
    }
    __syncthreads();
    if (tid < Kc) {
        #pragma unroll
        for (int g = 0; g < G; ++g) {
            float m = fmaxf(wmax[g][0], wmax[g][1]);
            pe[g] = exp2f((lp[g] - m) * 1.4426950408889634f);
            float s = pe[g];
            #pragma unroll
            for (int off = 32; off > 0; off >>= 1)
                s += __shfl_xor(s, off, 64);
            if ((tid & 63) == 0) wsum[g][tid >> 6] = s;
        }
    }
    __syncthreads();
    if (tid < Kc) {
        #pragma unroll
        for (int g = 0; g < G; ++g) {
            float Z = wsum[g][0] + wsum[g][1];
            pn[g][tid] = pe[g] * __builtin_amdgcn_rcpf(Z);
        }
    }
    __syncthreads();

    // ---------------- pass 2: gradient, thread = d ----------------
    float xg[G], O[G] = {0.0f, 0.0f};
    #pragma unroll
    for (int g = 0; g < G; ++g) xg[g] = x_lds[g][tid];

    #pragma unroll 4
    for (int k = 0; k < Kc; ++k) {
        float c  = centers[k * Dc + tid];   // coalesced: consecutive d
        float sd = stds[k * Dc + tid];
        float s2 = sd * sd;
        #pragma unroll
        for (int g = 0; g < G; ++g) {
            float var  = fmaf(e[g], s2, onee[g]);
            float rv   = __builtin_amdgcn_rcpf(var);
            float diff = fmaf(na[g], c, xg[g]);
            O[g] = fmaf(pn[g][k], diff * rv, O[g]);
        }
    }
    #pragma unroll
    for (int g = 0; g < G; ++g)
        out[(b0 + g) * Dc + tid] = sg[g] * O[g];
}

extern "C" void kernel_launch(void* const* d_in, const int* in_sizes, int n_in,
                              void* d_out, int out_size, void* d_ws, size_t ws_size,
                              hipStream_t stream) {
    const float* x       = (const float*)d_in[0];
    const float* t       = (const float*)d_in[1];
    const float* centers = (const float*)d_in[2];
    const float* stds    = (const float*)d_in[3];
    const float* weights = (const float*)d_in[4];
    float* outp = (float*)d_out;

    float* CT = (float*)d_ws;          // [D][K]
    float* AT = CT + Kc * Dc;          // [D][K] = stds^2 - 1

    const int B = in_sizes[1];         // 4096

    prep_kernel<<<(Kc * Dc + 255) / 256, 256, 0, stream>>>(centers, stds, CT, AT);
    score_kernel<<<B / G, 256, 0, stream>>>(x, t, centers, stds, weights, CT, AT, outp);
}

// Round 2
// 114.948 us; speedup vs baseline: 1.0719x; 1.0719x over previous
//
#include <hip/hip_runtime.h>
#include <math.h>

// B=4096, K=128, D=256.
// out[b,d] = sqrt(1-e) * sum_k p_k * (x - a*c)/var,  var = e*(s^2-1)+1
// lp_k = -0.5*S1 - 128*ln2*S2 + ln w_k   (k-uniform const dropped)
//   S1 = sum_d diff^2/var, S2 = sum_d log2(var)
// Quad-combined division: a0/v0+a1/v1+a2/v2+a3/v3 = num/(v0v1v2v3), 1 rcp per 4 tuples.

constexpr int Kc = 128;
constexpr int Dc = 256;
constexpr int G  = 4;   // batch rows per block

typedef float f4 __attribute__((ext_vector_type(4)));

// prep: interleaved-transposed tables for pass-1 dwordx4 loads.
// CT4[(d>>2)*(K*4) + k*4 + (d&3)] = centers[k][d];  AT4 same for stds^2-1.
__global__ void prep_kernel(const float* __restrict__ centers,
                            const float* __restrict__ stds,
                            float* __restrict__ CT4, float* __restrict__ AT4) {
    int idx = blockIdx.x * blockDim.x + threadIdx.x;   // idx = k*Dc + d (read-coalesced)
    if (idx >= Kc * Dc) return;
    int k = idx >> 8;
    int d = idx & (Dc - 1);
    int o = (d >> 2) * (Kc * 4) + k * 4 + (d & 3);
    float c = centers[idx];
    float s = stds[idx];
    CT4[o] = c;
    AT4[o] = s * s - 1.0f;
}

__global__ __launch_bounds__(256) void score_kernel(
    const float* __restrict__ x, const float* __restrict__ t,
    const float* __restrict__ centers, const float* __restrict__ stds,
    const float* __restrict__ weights,
    const float* __restrict__ CT4, const float* __restrict__ AT4,
    float* __restrict__ out)
{
    const int b0  = blockIdx.x * G;
    const int tid = threadIdx.x;

    __shared__ __align__(16) float xT[Dc][G];   // x transposed: one b128 = 4 g's
    __shared__ float part1[G][2][Kc];
    __shared__ float partL[G][2][Kc];
    __shared__ __align__(16) float peT[Kc][G];  // unnormalized softmax numerators
    __shared__ float wmax[G][2];
    __shared__ float wsum[G][2];

    // per-row scalars (uniform; cheap to recompute per thread)
    float e[G], na[G], onee[G], sg[G];
    #pragma unroll
    for (int g = 0; g < G; ++g) {
        float tt = t[b0 + g];
        float Bt = fmaf(9.95f * tt, tt, 0.1f * tt);
        float ee = __expf(-Bt);
        e[g]    = ee;
        na[g]   = -sqrtf(ee);
        onee[g] = 1.0f - ee;
        sg[g]   = sqrtf(1.0f - ee);
    }

    #pragma unroll
    for (int g = 0; g < G; ++g)
        xT[tid][g] = x[(b0 + g) * Dc + tid];
    __syncthreads();

    // ---------------- pass 1: thread = (k, half-of-D) ----------------
    const int kk    = tid & (Kc - 1);
    const int half  = tid >> 7;
    const int dbase = half * (Dc / 2);

    const f4* CT4v = (const f4*)CT4;
    const f4* AT4v = (const f4*)AT4;
    const f4* xTv  = (const f4*)(&xT[0][0]);

    float acc1[G] = {0.f, 0.f, 0.f, 0.f};
    float accL[G] = {0.f, 0.f, 0.f, 0.f};

    for (int grp = 0; grp < 8; ++grp) {        // 8 groups x 4 quads x 4 d
        float prod[G] = {1.f, 1.f, 1.f, 1.f};
        #pragma unroll
        for (int q = 0; q < 4; ++q) {
            const int d0 = dbase + (grp * 4 + q) * 4;
            const int qi = (d0 >> 2) * Kc + kk;
            f4 c4  = CT4v[qi];                 // dwordx4, coalesced over kk
            f4 A4  = AT4v[qi];
            f4 xv0 = xTv[d0 + 0];              // LDS b128 broadcast (d wave-uniform)
            f4 xv1 = xTv[d0 + 1];
            f4 xv2 = xTv[d0 + 2];
            f4 xv3 = xTv[d0 + 3];
            #pragma unroll
            for (int g = 0; g < G; ++g) {
                float v0 = fmaf(e[g], A4[0], 1.0f);   // var in [0.25, 1]
                float v1 = fmaf(e[g], A4[1], 1.0f);
                float v2 = fmaf(e[g], A4[2], 1.0f);
                float v3 = fmaf(e[g], A4[3], 1.0f);
                float f0 = fmaf(na[g], c4[0], xv0[g]);
                float f1 = fmaf(na[g], c4[1], xv1[g]);
                float f2 = fmaf(na[g], c4[2], xv2[g]);
                float f3 = fmaf(na[g], c4[3], xv3[g]);
                float s0 = f0 * f0, s1 = f1 * f1, s2 = f2 * f2, s3 = f3 * f3;
                float d01 = v0 * v1, d23 = v2 * v3;
                float n01 = s0 * v1; n01 = fmaf(s1, v0, n01);
                float n23 = s2 * v3; n23 = fmaf(s3, v2, n23);
                float den = d01 * d23;                 // >= 0.25^4, also feeds log path
                float num = n01 * d23; num = fmaf(n23, d01, num);
                acc1[g] = fmaf(num, __builtin_amdgcn_rcpf(den), acc1[g]);
                prod[g] *= den;
            }
        }
        #pragma unroll
        for (int g = 0; g < G; ++g)
            accL[g] += __log2f(prod[g]);       // 1 log per 16 d (prod >= 0.25^16)
    }
    #pragma unroll
    for (int g = 0; g < G; ++g) {
        part1[g][half][kk] = acc1[g];
        partL[g][half][kk] = accL[g];
    }
    __syncthreads();

    // ---------------- softmax over k (threads < K, 2 full waves) ----------------
    float lpv[G];
    if (tid < Kc) {
        float lw = __logf(weights[tid]);
        #pragma unroll
        for (int g = 0; g < G; ++g) {
            float S1 = part1[g][0][tid] + part1[g][1][tid];
            float S2 = partL[g][0][tid] + partL[g][1][tid];
            lpv[g] = fmaf(-0.5f, S1, fmaf(-88.72283911167299f, S2, lw)); // 128*ln2
            float m = lpv[g];
            #pragma unroll
            for (int off = 32; off > 0; off >>= 1)
                m = fmaxf(m, __shfl_xor(m, off, 64));
            if ((tid & 63) == 0) wmax[g][tid >> 6] = m;
        }
    }
    __syncthreads();
    if (tid < Kc) {
        #pragma unroll
        for (int g = 0; g < G; ++g) {
            float m  = fmaxf(wmax[g][0], wmax[g][1]);
            float pe = __expf(lpv[g] - m);
            peT[tid][g] = pe;                  // unnormalized; 1/Z folded into epilogue
            float s = pe;
            #pragma unroll
            for (int off = 32; off > 0; off >>= 1)
                s += __shfl_xor(s, off, 64);
            if ((tid & 63) == 0) wsum[g][tid >> 6] = s;
        }
    }
    __syncthreads();

    // ---------------- pass 2: thread = d ----------------
    f4 xvv = xTv[tid];
    float O[G] = {0.f, 0.f, 0.f, 0.f};
    const f4* peTv = (const f4*)(&peT[0][0]);
    const float* cp = centers + tid;
    const float* sp = stds + tid;

    for (int kq = 0; kq < 32; ++kq) {
        const int k0 = kq * 4;
        float c0 = cp[(k0 + 0) * Dc];          // coalesced over tid; imm offsets
        float c1 = cp[(k0 + 1) * Dc];
        float c2 = cp[(k0 + 2) * Dc];
        float c3 = cp[(k0 + 3) * Dc];
        float t0 = sp[(k0 + 0) * Dc];
        float t1 = sp[(k0 + 1) * Dc];
        float t2 = sp[(k0 + 2) * Dc];
        float t3 = sp[(k0 + 3) * Dc];
        f4 p0 = peTv[k0 + 0];                  // LDS b128 broadcast
        f4 p1 = peTv[k0 + 1];
        f4 p2 = peTv[k0 + 2];
        f4 p3 = peTv[k0 + 3];
        float s20 = t0 * t0, s21 = t1 * t1, s22 = t2 * t2, s23 = t3 * t3;
        #pragma unroll
        for (int g = 0; g < G; ++g) {
            float v0 = fmaf(e[g], s20, onee[g]);
            float v1 = fmaf(e[g], s21, onee[g]);
            float v2 = fmaf(e[g], s22, onee[g]);
            float v3 = fmaf(e[g], s23, onee[g]);
            float f0 = fmaf(na[g], c0, xvv[g]);
            float f1 = fmaf(na[g], c1, xvv[g]);
            float f2 = fmaf(na[g], c2, xvv[g]);
            float f3 = fmaf(na[g], c3, xvv[g]);
            float u0 = p0[g] * f0;
            float u1 = p1[g] * f1;
            float u2 = p2[g] * f2;
            float u3 = p3[g] * f3;
            float d01 = v0 * v1, d23 = v2 * v3;
            float n01 = u0 * v1; n01 = fmaf(u1, v0, n01);
            float n23 = u2 * v3; n23 = fmaf(u3, v2, n23);
            float den = d01 * d23;
            float num = n01 * d23; num = fmaf(n23, d01, num);
            O[g] = fmaf(num, __builtin_amdgcn_rcpf(den), O[g]);
        }
    }

    #pragma unroll
    for (int g = 0; g < G; ++g) {
        float Z = wsum[g][0] + wsum[g][1];
        out[(b0 + g) * Dc + tid] = sg[g] * __builtin_amdgcn_rcpf(Z) * O[g];
    }
}

extern "C" void kernel_launch(void* const* d_in, const int* in_sizes, int n_in,
                              void* d_out, int out_size, void* d_ws, size_t ws_size,
                              hipStream_t stream) {
    const float* x       = (const float*)d_in[0];
    const float* t       = (const float*)d_in[1];
    const float* centers = (const float*)d_in[2];
    const float* stds    = (const float*)d_in[3];
    const float* weights = (const float*)d_in[4];
    float* outp = (float*)d_out;

    float* CT4 = (float*)d_ws;           // [D/4][K][4]
    float* AT4 = CT4 + Kc * Dc;          // [D/4][K][4] of stds^2 - 1

    const int B = in_sizes[1];           // 4096

    prep_kernel<<<(Kc * Dc + 255) / 256, 256, 0, stream>>>(centers, stds, CT4, AT4);
    score_kernel<<<B / G, 256, 0, stream>>>(x, t, centers, stds, weights, CT4, AT4, outp);
}

// Round 3
// 102.091 us; speedup vs baseline: 1.2068x; 1.1259x over previous
//
#include <hip/hip_runtime.h>
#include <math.h>

// B=4096, K=128, D=256.
// out[b,d] = sqrt(1-e) * sum_k p_k * (x - a*c)/var,  var = 1 + e*(s^2-1)
// lp_k = -0.5*S1 - 128*ln2*S2 + ln w_k  (k-uniform const dropped)
//   S1 = sum_d diff^2/var, S2 = sum_d log2(var)
// Quad-combined division (1 rcp / 4 d-tuples) + packed 2xf32 math: the two
// f2 lanes are two batch rows (g-pair) sharing every table value.

constexpr int Kc = 128;
constexpr int Dc = 256;
constexpr int G  = 4;   // batch rows per block (2 f2 pairs)

typedef float f2 __attribute__((ext_vector_type(2)));
typedef float f4 __attribute__((ext_vector_type(4)));

static __device__ __forceinline__ f2 fma2(f2 a, f2 b, f2 c) {
    return __builtin_elementwise_fma(a, b, c);
}
static __device__ __forceinline__ f2 splat2(float s) { return (f2){s, s}; }

// prep: CA8[(d>>2)][k][8] = {c0,c1,c2,c3,A0,A1,A2,A3} (pass-1, transposed);
//       P2[k*Dc+d] = {c, A} (pass-2), A = s^2-1.
__global__ void prep_kernel(const float* __restrict__ centers,
                            const float* __restrict__ stds,
                            float* __restrict__ CA8, f2* __restrict__ P2) {
    int idx = blockIdx.x * blockDim.x + threadIdx.x;   // k*Dc + d, read-coalesced
    if (idx >= Kc * Dc) return;
    int k = idx >> 8;
    int d = idx & (Dc - 1);
    float c = centers[idx];
    float s = stds[idx];
    float A = s * s - 1.0f;
    int o = (d >> 2) * (Kc * 8) + k * 8 + (d & 3);
    CA8[o]     = c;
    CA8[o + 4] = A;
    P2[idx] = (f2){c, A};
}

__global__ __launch_bounds__(256, 6) void score_kernel(
    const float* __restrict__ x, const float* __restrict__ t,
    const float* __restrict__ weights,
    const float* __restrict__ CA8, const f2* __restrict__ P2,
    float* __restrict__ out)
{
    const int b0  = blockIdx.x * G;
    const int tid = threadIdx.x;

    __shared__ __align__(16) float xT[Dc][G];   // x transposed
    __shared__ float part1[G][2][Kc];
    __shared__ float partL[G][2][Kc];
    __shared__ __align__(16) float peT[Kc][G];  // unnormalized softmax numerators
    __shared__ float wmax[G][2];
    __shared__ float wsum[G][2];

    // per-row scalars
    float e[G], na[G], sg[G];
    #pragma unroll
    for (int g = 0; g < G; ++g) {
        float tt = t[b0 + g];
        float Bt = fmaf(9.95f * tt, tt, 0.1f * tt);
        float ee = __expf(-Bt);
        e[g]  = ee;
        na[g] = -sqrtf(ee);
        sg[g] = sqrtf(1.0f - ee);
    }
    f2 e2[2]  = {{e[0], e[1]}, {e[2], e[3]}};
    f2 na2[2] = {{na[0], na[1]}, {na[2], na[3]}};
    const f2 one2 = {1.0f, 1.0f};

    #pragma unroll
    for (int g = 0; g < G; ++g)
        xT[tid][g] = x[(b0 + g) * Dc + tid];
    __syncthreads();

    // ---------------- pass 1: thread = (k, half-of-D) ----------------
    const int kk    = tid & (Kc - 1);
    const int half  = tid >> 7;
    const int dbase = half * (Dc / 2);

    const f4* xTv = (const f4*)(&xT[0][0]);

    f2 acc1[2] = {{0.f, 0.f}, {0.f, 0.f}};
    float accL[G] = {0.f, 0.f, 0.f, 0.f};

    for (int grp = 0; grp < 8; ++grp) {
        f2 prod[2] = {{1.f, 1.f}, {1.f, 1.f}};
        #pragma unroll
        for (int q = 0; q < 4; ++q) {
            const int d0 = dbase + (grp * 4 + q) * 4;
            const float* base = CA8 + ((size_t)(d0 >> 2) * Kc + kk) * 8;
            f4 c4 = *(const f4*)base;          // dwordx4, coalesced over kk
            f4 A4 = *(const f4*)(base + 4);    // same addr + imm 16
            f4 xv0 = xTv[d0 + 0];              // LDS b128 broadcast (d uniform)
            f4 xv1 = xTv[d0 + 1];
            f4 xv2 = xTv[d0 + 2];
            f4 xv3 = xTv[d0 + 3];
            #pragma unroll
            for (int p = 0; p < 2; ++p) {
                f2 ep = e2[p], nap = na2[p];
                f2 x0 = {xv0[2*p], xv0[2*p+1]};
                f2 x1 = {xv1[2*p], xv1[2*p+1]};
                f2 x2 = {xv2[2*p], xv2[2*p+1]};
                f2 x3 = {xv3[2*p], xv3[2*p+1]};
                f2 v0 = fma2(ep, splat2(A4[0]), one2);   // var in [0.25,1]
                f2 v1 = fma2(ep, splat2(A4[1]), one2);
                f2 v2 = fma2(ep, splat2(A4[2]), one2);
                f2 v3 = fma2(ep, splat2(A4[3]), one2);
                f2 f0 = fma2(nap, splat2(c4[0]), x0);
                f2 f1 = fma2(nap, splat2(c4[1]), x1);
                f2 f2_ = fma2(nap, splat2(c4[2]), x2);
                f2 f3 = fma2(nap, splat2(c4[3]), x3);
                f2 s0 = f0 * f0, s1 = f1 * f1, s2 = f2_ * f2_, s3 = f3 * f3;
                f2 d01 = v0 * v1, d23 = v2 * v3;
                f2 n01 = fma2(s1, v0, s0 * v1);
                f2 n23 = fma2(s3, v2, s2 * v3);
                f2 den = d01 * d23;                      // >= 0.25^4
                f2 num = fma2(n23, d01, n01 * d23);
                f2 r = {__builtin_amdgcn_rcpf(den[0]),
                        __builtin_amdgcn_rcpf(den[1])};
                acc1[p] = fma2(num, r, acc1[p]);
                prod[p] = prod[p] * den;
            }
        }
        accL[0] += __log2f(prod[0][0]);        // 1 log per 16 d per g
        accL[1] += __log2f(prod[0][1]);
        accL[2] += __log2f(prod[1][0]);
        accL[3] += __log2f(prod[1][1]);
    }
    #pragma unroll
    for (int p = 0; p < 2; ++p) {
        part1[2*p  ][half][kk] = acc1[p][0];
        part1[2*p+1][half][kk] = acc1[p][1];
    }
    #pragma unroll
    for (int g = 0; g < G; ++g)
        partL[g][half][kk] = accL[g];
    __syncthreads();

    // ---------------- softmax over k (threads < K, 2 full waves) ----------------
    float lpv[G];
    if (tid < Kc) {
        float lw = __logf(weights[tid]);
        #pragma unroll
        for (int g = 0; g < G; ++g) {
            float S1 = part1[g][0][tid] + part1[g][1][tid];
            float S2 = partL[g][0][tid] + partL[g][1][tid];
            lpv[g] = fmaf(-0.5f, S1, fmaf(-88.72283911167299f, S2, lw)); // 128*ln2
            float m = lpv[g];
            #pragma unroll
            for (int off = 32; off > 0; off >>= 1)
                m = fmaxf(m, __shfl_xor(m, off, 64));
            if ((tid & 63) == 0) wmax[g][tid >> 6] = m;
        }
    }
    __syncthreads();
    if (tid < Kc) {
        #pragma unroll
        for (int g = 0; g < G; ++g) {
            float m  = fmaxf(wmax[g][0], wmax[g][1]);
            float pe = __expf(lpv[g] - m);
            peT[tid][g] = pe;                  // unnormalized; 1/Z in epilogue
            float s = pe;
            #pragma unroll
            for (int off = 32; off > 0; off >>= 1)
                s += __shfl_xor(s, off, 64);
            if ((tid & 63) == 0) wsum[g][tid >> 6] = s;
        }
    }
    __syncthreads();

    // ---------------- pass 2: thread = d ----------------
    f4 xvv = xTv[tid];
    f2 xp[2] = {{xvv[0], xvv[1]}, {xvv[2], xvv[3]}};
    f2 O[2] = {{0.f, 0.f}, {0.f, 0.f}};
    const f4* peTv = (const f4*)(&peT[0][0]);
    const f2* pp = P2 + tid;

    for (int kq = 0; kq < 32; ++kq) {
        const int k0 = kq * 4;
        f2 ca0 = pp[(k0 + 0) * Dc];            // dwordx2 {c,A}, coalesced
        f2 ca1 = pp[(k0 + 1) * Dc];
        f2 ca2 = pp[(k0 + 2) * Dc];
        f2 ca3 = pp[(k0 + 3) * Dc];
        f4 p0 = peTv[k0 + 0];                  // LDS b128 broadcast
        f4 p1 = peTv[k0 + 1];
        f4 p2 = peTv[k0 + 2];
        f4 p3 = peTv[k0 + 3];
        #pragma unroll
        for (int p = 0; p < 2; ++p) {
            f2 ep = e2[p], nap = na2[p];
            f2 v0 = fma2(ep, splat2(ca0[1]), one2);
            f2 v1 = fma2(ep, splat2(ca1[1]), one2);
            f2 v2 = fma2(ep, splat2(ca2[1]), one2);
            f2 v3 = fma2(ep, splat2(ca3[1]), one2);
            f2 f0 = fma2(nap, splat2(ca0[0]), xp[p]);
            f2 f1 = fma2(nap, splat2(ca1[0]), xp[p]);
            f2 f2_ = fma2(nap, splat2(ca2[0]), xp[p]);
            f2 f3 = fma2(nap, splat2(ca3[0]), xp[p]);
            f2 u0 = (f2){p0[2*p], p0[2*p+1]} * f0;
            f2 u1 = (f2){p1[2*p], p1[2*p+1]} * f1;
            f2 u2 = (f2){p2[2*p], p2[2*p+1]} * f2_;
            f2 u3 = (f2){p3[2*p], p3[2*p+1]} * f3;
            f2 d01 = v0 * v1, d23 = v2 * v3;
            f2 n01 = fma2(u1, v0, u0 * v1);
            f2 n23 = fma2(u3, v2, u2 * v3);
            f2 den = d01 * d23;
            f2 num = fma2(n23, d01, n01 * d23);
            f2 r = {__builtin_amdgcn_rcpf(den[0]),
                    __builtin_amdgcn_rcpf(den[1])};
            O[p] = fma2(num, r, O[p]);
        }
    }

    #pragma unroll
    for (int p = 0; p < 2; ++p) {
        #pragma unroll
        for (int j = 0; j < 2; ++j) {
            int g = 2 * p + j;
            float Z = wsum[g][0] + wsum[g][1];
            out[(b0 + g) * Dc + tid] = sg[g] * __builtin_amdgcn_rcpf(Z) * O[p][j];
        }
    }
}

extern "C" void kernel_launch(void* const* d_in, const int* in_sizes, int n_in,
                              void* d_out, int out_size, void* d_ws, size_t ws_size,
                              hipStream_t stream) {
    const float* x       = (const float*)d_in[0];
    const float* t       = (const float*)d_in[1];
    const float* centers = (const float*)d_in[2];
    const float* stds    = (const float*)d_in[3];
    const float* weights = (const float*)d_in[4];
    float* outp = (float*)d_out;

    float* CA8 = (float*)d_ws;                    // [D/4][K][8]  (256 KB)
    f2*    P2  = (f2*)(CA8 + Kc * Dc * 2);        // [K][D] {c,A} (256 KB)

    const int B = in_sizes[1];                    // 4096

    prep_kernel<<<(Kc * Dc + 255) / 256, 256, 0, stream>>>(centers, stds, CA8, P2);
    score_kernel<<<B / G, 256, 0, stream>>>(x, t, weights, CA8, P2, outp);
}